// Round 8
// baseline (82527.917 us; speedup 1.0000x reference)
//
#include <hip/hip_runtime.h>
#include <math.h>

namespace {

typedef unsigned long long u64;

constexpr int cH  = 1024;
constexpr int cZ  = 256;
constexpr int cB  = 64;
constexpr int cT  = 256;
constexpr int cR  = 389;
constexpr int cSC = 89;
constexpr int cPF = 300;
constexpr int WSTR = 400;               // padded encoder w_ih / x stride (floats) = 100 f4
constexpr float INV_S = 0.9999950000374997f;  // 1/sqrt(1+1e-5)

__device__ __forceinline__ void fma4(float4& a, const float4 x, const float4 w){
  a.x = fmaf(x.x, w.x, a.x);
  a.y = fmaf(x.y, w.y, a.y);
  a.z = fmaf(x.z, w.z, a.z);
  a.w = fmaf(x.w, w.w, a.w);
}
__device__ __forceinline__ float fold4(const float4 a){ return (a.x + a.y) + (a.z + a.w); }
__device__ __forceinline__ float4 z4(){ return make_float4(0.f, 0.f, 0.f, 0.f); }
__device__ __forceinline__ float sigm(float x){ return 1.f / (1.f + expf(-x)); }

// ---- guaranteed-coherent primitives ----
__device__ __forceinline__ void cfence(){ asm volatile("" ::: "memory"); }
__device__ __forceinline__ u64 ld_u64(const u64* p){
  return __hip_atomic_load(p, __ATOMIC_RELAXED, __HIP_MEMORY_SCOPE_AGENT);
}
__device__ __forceinline__ float ld_scal(const float* p){
  return __hip_atomic_load(p, __ATOMIC_RELAXED, __HIP_MEMORY_SCOPE_AGENT);
}
__device__ __forceinline__ void st_scal(float* p, float v){
  __hip_atomic_store(p, v, __ATOMIC_RELAXED, __HIP_MEMORY_SCOPE_AGENT);
}

// ---- two-level group barrier; RELEASE arrival orders prior agent stores ----
__device__ __forceinline__ void gbarN(unsigned* base, int sub, unsigned subCnt,
                                      int nsub, unsigned rootCnt){
  __syncthreads();
  if (threadIdx.x == 0){
    cfence();
    unsigned* root = base + nsub * 16;
    unsigned* gen  = base + nsub * 16 + 16;
    const unsigned g = __hip_atomic_load(gen, __ATOMIC_RELAXED, __HIP_MEMORY_SCOPE_AGENT);
    const unsigned a = __hip_atomic_fetch_add(base + sub * 16, 1u,
                         __ATOMIC_RELEASE, __HIP_MEMORY_SCOPE_AGENT);
    bool flip = false;
    if (a == subCnt - 1u){
      const unsigned r = __hip_atomic_fetch_add(root, 1u,
                           __ATOMIC_RELEASE, __HIP_MEMORY_SCOPE_AGENT);
      if (r == rootCnt - 1u){
        for (int t = 0; t < nsub; ++t)
          __hip_atomic_store(base + t * 16, 0u, __ATOMIC_RELAXED, __HIP_MEMORY_SCOPE_AGENT);
        __hip_atomic_store(root, 0u, __ATOMIC_RELAXED, __HIP_MEMORY_SCOPE_AGENT);
        __hip_atomic_store(gen, g + 1u, __ATOMIC_RELEASE, __HIP_MEMORY_SCOPE_AGENT);
        flip = true;
      }
    }
    if (!flip){
      while (__hip_atomic_load(gen, __ATOMIC_RELAXED, __HIP_MEMORY_SCOPE_AGENT) == g)
        __builtin_amdgcn_s_sleep(1);
    }
    cfence();
  }
  __syncthreads();
}

// ---------------------------------------------------------------- prep kernels
__global__ __launch_bounds__(256) void init_kernel(float* hf0, float* hb0, float* dout_tail,
                                                   unsigned* barE, unsigned* barD){
  const int idx = blockIdx.x * 256 + threadIdx.x;
  const int stride = gridDim.x * 256;
  for (int i = idx; i < cB * cH; i += stride){ hf0[i] = 0.f; hb0[i] = 0.f; }
  for (int i = idx; i < 2 * cB * cZ; i += stride) dout_tail[i] = 0.f;
  for (int i = idx; i < 2048; i += stride) barE[i] = 0u;
  for (int i = idx; i < 1024; i += stride) barD[i] = 0u;
}

__global__ __launch_bounds__(256) void pad_wih_kernel(const float* __restrict__ w,
                                                      float* __restrict__ wp){
  const int idx = blockIdx.x * 256 + threadIdx.x;
  const int stride = gridDim.x * 256;
  const int n = 3 * cH * WSTR;
  for (int i = idx; i < n; i += stride){
    const int r = i / WSTR, c = i - r * WSTR;
    wp[i] = (c < cR) ? w[(size_t)r * cR + c] : 0.f;
  }
}

__global__ __launch_bounds__(256) void pad_x_kernel(const float* __restrict__ x,
                                                    float* __restrict__ xp){
  const int idx = blockIdx.x * 256 + threadIdx.x;
  const int stride = gridDim.x * 256;
  const int n = cT * cB * WSTR;
  for (int i = idx; i < n; i += stride){
    const int r = i / WSTR, c = i - r * WSTR;
    xp[i] = (c < cR) ? x[(size_t)r * cR + c] : 0.f;
  }
}

__global__ __launch_bounds__(256) void pad_wsc_kernel(const float* __restrict__ w_ih0,
                                                      float* __restrict__ wsc){
  const int idx = blockIdx.x * 256 + threadIdx.x;
  const int stride = gridDim.x * 256;
  const int n = 3 * cH * 96;
  for (int i = idx; i < n; i += stride){
    const int r = i / 96, c = i - r * 96;
    wsc[i] = (c < cSC) ? w_ih0[(size_t)r * 645 + 300 + c] : 0.f;
  }
}

// ---------------------------------------------------------------- encoder (persistent)
// 512 blocks: xcd=bid&7, slot=bid>>3 (64): dir=slot>>5, bhalf=(slot>>4)&1, k16=slot&15;
// kblk = xcd*16+k16 (0..127, 8 k-rows), bhalf -> 32 batches.
// tid 512: seg=tid>>6 (8 col-segs); lane: tx=lane&7, ty=lane>>3; b = tx+8*jj (jj 0..3).
__global__ __launch_bounds__(512, 4) void enc_persist(
    const float* __restrict__ xp,
    const float* __restrict__ wihPf, const float* __restrict__ whh_f,
    const float* __restrict__ bih_f, const float* __restrict__ bhh_f,
    const float* __restrict__ wihPb, const float* __restrict__ whh_b,
    const float* __restrict__ bih_b, const float* __restrict__ bhh_b,
    float* __restrict__ hfA, float* __restrict__ hfB,
    float* __restrict__ hbA, float* __restrict__ hbB,
    unsigned* __restrict__ barE)
{
  const int bid   = blockIdx.x;
  const int xcd   = bid & 7;
  const int slot  = bid >> 3;
  const int dir   = slot >> 5;
  const int bhalf = (slot >> 4) & 1;
  const int k16   = slot & 15;
  const int kblk  = xcd * 16 + k16;
  unsigned* bar   = barE + (dir * 2 + bhalf) * 512;

  const float* wih = dir ? wihPb : wihPf;
  const float* whh = dir ? whh_b : whh_f;
  const float* bih = dir ? bih_b : bih_f;
  const float* bhh = dir ? bhh_b : bhh_f;
  float* bufA = dir ? hbA : hfA;
  float* bufB = dir ? hbB : hfB;

  const int tid   = threadIdx.x;
  const int seg   = tid >> 6;            // 0..7
  const int lane  = tid & 63;
  const int tx    = lane & 7;
  const int ty    = lane >> 3;
  const int kbase = kblk * 8;
  const int bbase = bhalf * 32;
  const int k     = kbase + ty;

  // arena: 32 rows x 129 f4 = 66 KB.  part overlays floats [0, 8448).
  __shared__ alignas(16) float sh[32 * 516];
  float4* sh4 = (float4*)sh;
  float*  part = sh;                     // PART(seg,g,ty,b) time-disjoint from stage
  #define EPART(s,g,r,b) part[(((s)*4+(g))*8+(r))*33+(b)]

  const float4* w0i = (const float4*)wih + (size_t)k * 100;
  const float4* w1i = (const float4*)wih + (size_t)(cH + k) * 100;
  const float4* w2i = (const float4*)wih + (size_t)(2*cH + k) * 100;
  const float4* w0h = (const float4*)whh + (size_t)k * 256;
  const float4* w1h = (const float4*)whh + (size_t)(cH + k) * 256;
  const float4* w2h = (const float4*)whh + (size_t)(2*cH + k) * 256;

  auto stageE = [&](const float* hin, int p){
    const u64* s8 = (const u64*)hin;
    u64* d8 = (u64*)sh;
    u64 tmp[16];
    #pragma unroll
    for (int i = 0; i < 16; ++i){
      const int e = i * 512 + tid;
      tmp[i] = ld_u64(s8 + (size_t)(bbase + (e >> 8)) * 512 + p * 256 + (e & 255));
    }
    #pragma unroll
    for (int i = 0; i < 16; ++i){
      const int e = i * 512 + tid;
      d8[(e >> 8) * 258 + (e & 255)] = tmp[i];
    }
  };

  for (int t = 0; t < cT; ++t){
    const float* hin = (t & 1) ? bufB : bufA;
    float*      hout = (t & 1) ? bufA : bufB;
    const int tt = dir ? (cT - 1 - t) : t;

    float4 R[4], Z[4], NI[4], NH[4];
    #pragma unroll
    for (int jj = 0; jj < 4; ++jj){ R[jj]=z4(); Z[jj]=z4(); NI[jj]=z4(); NH[jj]=z4(); }

    // ---- phase 1: x @ w_ih^T (padded f4)
    {
      const float4* xr[4];
      #pragma unroll
      for (int jj = 0; jj < 4; ++jj)
        xr[jj] = (const float4*)xp + (size_t)(tt * cB + bbase + tx + 8*jj) * 100;
      const int c0 = seg * 13;
      const int c1 = (c0 + 13 < 100) ? c0 + 13 : 100;
      for (int c = c0; c < c1; ++c){
        const float4 w0v = w0i[c], w1v = w1i[c], w2v = w2i[c];
        #pragma unroll
        for (int jj = 0; jj < 4; ++jj){
          const float4 a = xr[jj][c];
          fma4(R[jj], a, w0v); fma4(Z[jj], a, w1v); fma4(NI[jj], a, w2v);
        }
      }
    }

    // ---- phase 2: h @ w_hh^T, two staged halves (16 f4 cols per seg per half)
    #pragma unroll 1
    for (int p = 0; p < 2; ++p){
      stageE(hin, p);
      __syncthreads();
      {
        const float4* wp0 = w0h + p * 128;
        const float4* wp1 = w1h + p * 128;
        const float4* wp2 = w2h + p * 128;
        #pragma unroll 4
        for (int c = 0; c < 16; ++c){
          const int cc = seg * 16 + c;
          const float4 w0v = wp0[cc], w1v = wp1[cc], w2v = wp2[cc];
          #pragma unroll
          for (int jj = 0; jj < 4; ++jj){
            const float4 a = sh4[(tx + 8*jj)*129 + cc];
            fma4(R[jj], a, w0v); fma4(Z[jj], a, w1v); fma4(NH[jj], a, w2v);
          }
        }
      }
      __syncthreads();
    }

    // ---- part overlay write (stage reads done), reduce, store
    #pragma unroll
    for (int jj = 0; jj < 4; ++jj){
      const int b = tx + 8*jj;
      EPART(seg,0,ty,b) = fold4(R[jj]);
      EPART(seg,1,ty,b) = fold4(Z[jj]);
      EPART(seg,2,ty,b) = fold4(NI[jj]);
      EPART(seg,3,ty,b) = fold4(NH[jj]);
    }
    __syncthreads();
    if (tid < 256){
      const int row = tid >> 5, bb = tid & 31;
      float rs=0.f, zs=0.f, nis=0.f, nhs=0.f;
      #pragma unroll
      for (int s = 0; s < 8; ++s){
        rs += EPART(s,0,row,bb); zs += EPART(s,1,row,bb);
        nis += EPART(s,2,row,bb); nhs += EPART(s,3,row,bb);
      }
      const int kk = kbase + row, gb = bbase + bb;
      const float r  = sigm(rs + bih[kk] + bhh[kk]);
      const float zg = sigm(zs + bih[cH + kk] + bhh[cH + kk]);
      const float nn = tanhf(nis + bih[2*cH + kk] + r * (nhs + bhh[2*cH + kk]));
      const float hp = ld_scal(&hin[(size_t)gb * cH + kk]);
      st_scal(&hout[(size_t)gb * cH + kk], (1.f - zg) * nn + zg * hp);
    }
    gbarN(bar, k16, 8u, 16, 16u);
  }
  #undef EPART
}

// ---------------------------------------------------------------- decoder (persistent)
// 512 blocks: xcd=bid&7, slot=bid>>3 (64): kq = xcd*16 + (slot>>2) (0..127, 8 k-rows),
// bq = slot&3 (16 batches).  One 512-block barrier domain (32 subs x 16).
// tid 512: seg=tid>>6 (8 col-segs of 32 f4); lane: tx=lane&7, ty=lane>>3; b = tx+8*jj (jj 0..1).
__global__ __launch_bounds__(512, 4) void dec_persist(
    const float* __restrict__ x,
    const float* __restrict__ hfA, const float* __restrict__ hbA,
    const float* __restrict__ w_mu, const float* __restrict__ b_mu,
    const float* __restrict__ w_init, const float* __restrict__ b_init,
    const float* __restrict__ w_ih0,
    const float* __restrict__ wsc,   const float* __restrict__ w_hh0,
    const float* __restrict__ b_ih0, const float* __restrict__ b_hh0,
    const float* __restrict__ w_ih1, const float* __restrict__ w_hh1,
    const float* __restrict__ b_ih1, const float* __restrict__ b_hh1,
    const float* __restrict__ w_ih2, const float* __restrict__ w_hh2,
    const float* __restrict__ b_ih2, const float* __restrict__ b_hh2,
    const float* __restrict__ w_out, const float* __restrict__ b_out,
    float* __restrict__ h0A, float* __restrict__ h0B,
    float* __restrict__ h1A, float* __restrict__ h1B,
    float* __restrict__ h2A, float* __restrict__ h2B,
    float* __restrict__ zbuf, float* __restrict__ lgbuf,
    float* __restrict__ dout,
    unsigned* __restrict__ barD)
{
  const int bid  = blockIdx.x;
  const int xcd  = bid & 7;
  const int slot = bid >> 3;
  const int kq   = xcd * 16 + (slot >> 2);
  const int bq   = slot & 3;
  const int kbase = kq * 8;
  const int bbase = bq * 16;
  const int tid = threadIdx.x;

  const int seg  = tid >> 6;
  const int lane = tid & 63;
  const int tx   = lane & 7;
  const int ty   = lane >> 3;
  const int k    = kbase + ty;

  // arena: 16 rows x 257 f4 = 65.8 KB.  Overlays (time-disjoint):
  //   part  floats [0, 4352)       (end-of-phase partials)
  //   LG    floats [0, 16*312)     (phase-A softmax rows)
  //   scs   floats [10240, +1600)  (staged scores, 16 x 100)
  __shared__ alignas(16) float arena[16 * 1028];
  __shared__ float ams[16];
  __shared__ float gz[3][8][16];

  float4* stg4 = (float4*)arena;
  float*  part = arena;
  #define DPART(s,g,r,b) part[(((s)*4+(g))*8+(r))*17+(b)]
  float*  scs  = arena + 10240;
  const float4* sc4 = (const float4*)(arena + 10240);

  #define GBD gbarN(barD, bid >> 4, 16u, 32, 32u)

  auto stageH = [&](const float* src){
    const u64* s8 = (const u64*)src;
    u64* d8 = (u64*)arena;
    u64 tmp[16];
    #pragma unroll
    for (int i = 0; i < 16; ++i){
      const int e = i * 512 + tid;
      tmp[i] = ld_u64(s8 + (size_t)(bbase + (e >> 9)) * 512 + (e & 511));
    }
    #pragma unroll
    for (int i = 0; i < 16; ++i){
      const int e = i * 512 + tid;
      d8[(e >> 9) * 514 + (e & 511)] = tmp[i];
    }
  };

  auto accH = [&](const float4* w0, const float4* w1, const float4* w2,
                  float4& A0, float4& A1, float4& B0, float4& B1,
                  float4& C0, float4& C1){
    #pragma unroll 4
    for (int c = 0; c < 32; ++c){
      const int cc = seg * 32 + c;
      const float4 w0v = w0[cc], w1v = w1[cc], w2v = w2[cc];
      const float4 aA = stg4[tx * 257 + cc];
      const float4 aB = stg4[(tx + 8) * 257 + cc];
      fma4(A0, aA, w0v); fma4(B0, aA, w1v); fma4(C0, aA, w2v);
      fma4(A1, aB, w0v); fma4(B1, aB, w1v); fma4(C1, aB, w2v);
    }
  };

  auto reduce_store = [&](const float* bi, const float* bhv,
                          const float* hprev, float* hout){
    __syncthreads();
    if (tid < 128){
      const int row = tid >> 4, b = tid & 15;
      float rs=0.f, zs=0.f, nis=0.f, nhs=0.f;
      #pragma unroll
      for (int s = 0; s < 8; ++s){
        rs += DPART(s,0,row,b); zs += DPART(s,1,row,b);
        nis += DPART(s,2,row,b); nhs += DPART(s,3,row,b);
      }
      const int kk = kbase + row, gb = bbase + b;
      const float r  = sigm(rs + bi[kk] + bhv[kk]);
      const float zg = sigm(zs + bi[cH + kk] + bhv[cH + kk]);
      const float nn = tanhf(nis + bi[2*cH + kk] + r * (nhs + bhv[2*cH + kk]));
      const float hp = ld_scal(&hprev[(size_t)gb * cH + kk]);
      st_scal(&hout[(size_t)gb * cH + kk], (1.f - zg) * nn + zg * hp);
    }
  };

  // fold: read lgbuf rows for this block's 16 batches, log-softmax, optional dout, argmax->ams
  auto fold16 = [&](int jm1, bool writeAms){
    const int team = tid >> 5, l32 = tid & 31;
    const int gb = bbase + team;
    {
      const u64* lb8 = (const u64*)lgbuf;
      u64* lr = (u64*)(arena + team * 312);
      for (int q = l32; q < 150; q += 32)
        lr[q] = ld_u64(lb8 + (size_t)gb * 150 + q);
    }
    __syncthreads();
    const float* lgr = arena + team * 312;
    float m[3], lse[3];
    #pragma unroll
    for (int g3 = 0; g3 < 3; ++g3){
      float mm = -INFINITY;
      for (int p = g3*100 + l32; p < g3*100 + 100; p += 32) mm = fmaxf(mm, lgr[p]);
      #pragma unroll
      for (int off = 16; off > 0; off >>= 1) mm = fmaxf(mm, __shfl_xor(mm, off, 32));
      float ss = 0.f;
      for (int p = g3*100 + l32; p < g3*100 + 100; p += 32) ss += expf(lgr[p] - mm);
      #pragma unroll
      for (int off = 16; off > 0; off >>= 1) ss += __shfl_xor(ss, off, 32);
      m[g3] = mm; lse[g3] = logf(ss);
    }
    float best = -INFINITY; int bidx = 0x7fffffff;
    for (int p = l32; p < cPF; p += 32){
      const int g3 = (p >= 200) ? 2 : ((p >= 100) ? 1 : 0);
      const float o = lgr[p] - m[g3] - lse[g3];
      if (kq == 0) dout[((size_t)gb * cT + jm1) * cPF + p] = o;
      if (o > best || (o == best && p < bidx)){ best = o; bidx = p; }
    }
    if (writeAms){
      #pragma unroll
      for (int off = 16; off > 0; off >>= 1){
        const float ob = __shfl_xor(best, off, 32);
        const int   oi = __shfl_xor(bidx, off, 32);
        if (ob > best || (ob == best && oi < bidx)){ best = ob; bidx = oi; }
      }
      if (l32 == 0) ams[team] = (float)bidx;
    }
  };

  // ================= prologue =================
  if (bid < cB){
    const int b = bid;
    float4* hl4 = (float4*)arena;
    hl4[tid] = (tid < 256) ? ((const float4*)hfA)[(size_t)b * 256 + tid]
                           : ((const float4*)hbA)[(size_t)b * 256 + (tid - 256)];
    __syncthreads();
    if (tid < 256){
      const float4* wr = (const float4*)w_mu + (size_t)tid * 512;
      float4 s = z4();
      #pragma unroll 4
      for (int c = 0; c < 512; ++c) fma4(s, hl4[c], wr[c]);
      st_scal(&zbuf[(size_t)b * cZ + tid], b_mu[tid] + fold4(s) * INV_S);
    }
  }
  GBD;
  {
    // stage z for this block's 16 batches (row stride 260 floats = 130 u64)
    {
      u64 tmp[4];
      const u64* zb8 = (const u64*)zbuf;
      u64* zl8 = (u64*)arena;
      #pragma unroll
      for (int q = 0; q < 4; ++q){
        const int e = q * 512 + tid;
        tmp[q] = ld_u64(zb8 + (size_t)(bbase + (e >> 7)) * 128 + (e & 127));
      }
      #pragma unroll
      for (int q = 0; q < 4; ++q){
        const int e = q * 512 + tid;
        zl8[(e >> 7) * 130 + (e & 127)] = tmp[q];
      }
    }
    __syncthreads();
    if (tid < 384){                         // gz: 3 gates x 8 rows x 16 batches
      const int g = tid >> 7, kr = (tid >> 4) & 7, b = tid & 15;
      const float* zr = arena + b * 260;
      const float* wrow = w_ih0 + (size_t)(g * cH + kbase + kr) * 645 + 389;
      float s = 0.f;
      #pragma unroll 4
      for (int d = 0; d < cZ; ++d) s = fmaf(zr[d], wrow[d], s);
      gz[g][kr][b] = s;
    }
    if (tid < 128){                         // hinit: 8 rows x 16 batches
      const int kr = tid >> 4, b = tid & 15;
      const float4* zr4 = (const float4*)(arena + b * 260);
      const float4* wr4 = (const float4*)w_init + (size_t)(kbase + kr) * 64;
      float4 s = z4();
      #pragma unroll 4
      for (int d = 0; d < 64; ++d) fma4(s, zr4[d], wr4[d]);
      st_scal(&h0A[(size_t)(bbase + b) * cH + kbase + kr],
              tanhf(b_init[kbase + kr] + fold4(s)));
    }
    __syncthreads();
  }
  GBD;

  // ================= main loop =================
  for (int j = 0; j < cT; ++j){
    const int par = j & 1;
    const float* h0p = par ? h0B : h0A;  float* h0n = par ? h0A : h0B;
    const float* h1p = par ? h1B : h1A;  float* h1n = par ? h1A : h1B;
    const float* h2p = par ? h2B : h2A;  float* h2n = par ? h2A : h2B;

    // ---- phase A: fold(prev) + layer 0
    {
      if (j == 0){
        if (tid < 16) ams[tid] = 299.f;
        const int team = tid >> 5, l32 = tid & 31;
        for (int c = l32; c < 96; c += 32) scs[team * 100 + c] = (c == 88) ? 1.f : 0.f;
      } else {
        fold16(j - 1, true);
        __syncthreads();
        const int team = tid >> 5, l32 = tid & 31;
        const int gb = bbase + team;
        for (int c = l32; c < 96; c += 32)
          scs[team * 100 + c] = (c < cSC) ? x[((size_t)(j - 1) * cB + gb) * cR + c] : 0.f;
      }
      __syncthreads();

      float4 R[2], Z[2], NI[2], NH[2];
      float sR[2], sZ[2], sNI[2];
      #pragma unroll
      for (int jj = 0; jj < 2; ++jj){
        R[jj]=z4(); Z[jj]=z4(); NI[jj]=z4(); NH[jj]=z4();
        sR[jj]=0.f; sZ[jj]=0.f; sNI[jj]=0.f;
      }
      {  // score GEMM: cols seg*3..+3 of 24 f4
        const float4* ws0 = (const float4*)wsc + (size_t)k * 24;
        const float4* ws1 = (const float4*)wsc + (size_t)(cH + k) * 24;
        const float4* ws2 = (const float4*)wsc + (size_t)(2*cH + k) * 24;
        #pragma unroll
        for (int c = 0; c < 3; ++c){
          const int cc = seg * 3 + c;
          const float4 w0v = ws0[cc], w1v = ws1[cc], w2v = ws2[cc];
          #pragma unroll
          for (int jj = 0; jj < 2; ++jj){
            const float4 a = sc4[(tx + 8*jj) * 25 + cc];
            fma4(R[jj], a, w0v); fma4(Z[jj], a, w1v); fma4(NI[jj], a, w2v);
          }
        }
      }
      if (seg == 0){  // one-hot gather + precomputed z-part
        #pragma unroll
        for (int jj = 0; jj < 2; ++jj){
          const int b = tx + 8*jj;
          const int am = (int)ams[b];
          sR[jj]  = w_ih0[(size_t)k * 645 + am]          + gz[0][ty][b];
          sZ[jj]  = w_ih0[(size_t)(cH + k) * 645 + am]   + gz[1][ty][b];
          sNI[jj] = w_ih0[(size_t)(2*cH + k) * 645 + am] + gz[2][ty][b];
        }
      }
      const float4* wh0 = (const float4*)w_hh0 + (size_t)k * 256;
      const float4* wh1 = (const float4*)w_hh0 + (size_t)(cH + k) * 256;
      const float4* wh2 = (const float4*)w_hh0 + (size_t)(2*cH + k) * 256;
      __syncthreads();
      stageH(h0p);  __syncthreads();
      accH(wh0, wh1, wh2, R[0], R[1], Z[0], Z[1], NH[0], NH[1]);
      __syncthreads();
      #pragma unroll
      for (int jj = 0; jj < 2; ++jj){
        const int b = tx + 8*jj;
        DPART(seg,0,ty,b) = fold4(R[jj]) + sR[jj];
        DPART(seg,1,ty,b) = fold4(Z[jj]) + sZ[jj];
        DPART(seg,2,ty,b) = fold4(NI[jj]) + sNI[jj];
        DPART(seg,3,ty,b) = fold4(NH[jj]);
      }
      reduce_store(b_ih0, b_hh0, h0p, h0n);
    }
    GBD;

    // ---- phases B, C: layers 1, 2
    #pragma unroll 1
    for (int L = 0; L < 2; ++L){
      const float* inG = (L == 0) ? h0n : h1n;
      const float* pvG = (L == 0) ? (j == 0 ? h0n : h1p) : (j == 0 ? h1n : h2p);
      const float* wih = (L == 0) ? w_ih1 : w_ih2;
      const float* whh = (L == 0) ? w_hh1 : w_hh2;
      const float* bi  = (L == 0) ? b_ih1 : b_ih2;
      const float* bhv = (L == 0) ? b_hh1 : b_hh2;
      float* outG      = (L == 0) ? h1n : h2n;

      float4 R[2], Z[2], NI[2], NH[2];
      #pragma unroll
      for (int jj = 0; jj < 2; ++jj){ R[jj]=z4(); Z[jj]=z4(); NI[jj]=z4(); NH[jj]=z4(); }
      const float4* wi0 = (const float4*)wih + (size_t)k * 256;
      const float4* wi1 = (const float4*)wih + (size_t)(cH + k) * 256;
      const float4* wi2 = (const float4*)wih + (size_t)(2*cH + k) * 256;
      const float4* wh0 = (const float4*)whh + (size_t)k * 256;
      const float4* wh1 = (const float4*)whh + (size_t)(cH + k) * 256;
      const float4* wh2 = (const float4*)whh + (size_t)(2*cH + k) * 256;

      stageH(inG);  __syncthreads();
      accH(wi0, wi1, wi2, R[0], R[1], Z[0], Z[1], NI[0], NI[1]);
      __syncthreads();
      stageH(pvG);  __syncthreads();
      accH(wh0, wh1, wh2, R[0], R[1], Z[0], Z[1], NH[0], NH[1]);
      __syncthreads();
      #pragma unroll
      for (int jj = 0; jj < 2; ++jj){
        const int b = tx + 8*jj;
        DPART(seg,0,ty,b) = fold4(R[jj]);
        DPART(seg,1,ty,b) = fold4(Z[jj]);
        DPART(seg,2,ty,b) = fold4(NI[jj]);
        DPART(seg,3,ty,b) = fold4(NH[jj]);
      }
      reduce_store(bi, bhv, pvG, outG);
      GBD;
    }

    // ---- phase D: distributed logits -> lgbuf (2-3 p-rows per kq)
    {
      const int p0 = (kq * 300) >> 7;
      const int p1 = ((kq + 1) * 300) >> 7;
      stageH(h2n);  __syncthreads();
      const int b16 = tid >> 5;           // 0..15
      const int cs  = tid & 31;           // 0..31
      for (int pr = p0; pr < p1; ++pr){
        const float4* wr = (const float4*)w_out + (size_t)pr * 256;
        const float4* av = stg4 + b16 * 257;
        float4 s = z4();
        #pragma unroll
        for (int u = 0; u < 8; ++u){
          const int cc = cs + u * 32;
          fma4(s, av[cc], wr[cc]);
        }
        float v = fold4(s);
        #pragma unroll
        for (int off = 16; off > 0; off >>= 1) v += __shfl_xor(v, off, 32);
        if (cs == 0)
          st_scal(&lgbuf[(size_t)(bbase + b16) * cPF + pr], v + b_out[pr]);
      }
      __syncthreads();
    }
    GBD;
  }

  // tail: fold for step 255 (dout only)
  if (kq == 0) fold16(cT - 1, false);
  #undef DPART
  #undef GBD
}

} // namespace

// ---------------------------------------------------------------- host
extern "C" void kernel_launch(void* const* d_in, const int* in_sizes, int n_in,
                              void* d_out, int out_size, void* d_ws, size_t ws_size,
                              hipStream_t stream)
{
  const float* x     = (const float*)d_in[0];
  const float* wih_f = (const float*)d_in[2];
  const float* whh_f = (const float*)d_in[3];
  const float* bih_f = (const float*)d_in[4];
  const float* bhh_f = (const float*)d_in[5];
  const float* wih_b = (const float*)d_in[6];
  const float* whh_b = (const float*)d_in[7];
  const float* bih_b = (const float*)d_in[8];
  const float* bhh_b = (const float*)d_in[9];
  const float* w_mu  = (const float*)d_in[10];
  const float* b_mu  = (const float*)d_in[11];
  const float* w_init= (const float*)d_in[14];
  const float* b_init= (const float*)d_in[15];
  const float* w_ih0 = (const float*)d_in[16];
  const float* w_hh0 = (const float*)d_in[17];
  const float* b_ih0 = (const float*)d_in[18];
  const float* b_hh0 = (const float*)d_in[19];
  const float* w_ih1 = (const float*)d_in[20];
  const float* w_hh1 = (const float*)d_in[21];
  const float* b_ih1 = (const float*)d_in[22];
  const float* b_hh1 = (const float*)d_in[23];
  const float* w_ih2 = (const float*)d_in[24];
  const float* w_hh2 = (const float*)d_in[25];
  const float* b_ih2 = (const float*)d_in[26];
  const float* b_hh2 = (const float*)d_in[27];
  const float* w_out = (const float*)d_in[28];
  const float* b_out = (const float*)d_in[29];
  float* dout = (float*)d_out;

  float* ws = (float*)d_ws;
  float* wihfP = ws; ws += (size_t)3 * cH * WSTR;     // 4.9 MB
  float* wihbP = ws; ws += (size_t)3 * cH * WSTR;     // 4.9 MB
  float* xp    = ws; ws += (size_t)cT * cB * WSTR;    // 26.2 MB
  float* wsc   = ws; ws += (size_t)3 * cH * 96;       // 1.2 MB
  float* hfA = ws; ws += cB * cH;  float* hfB = ws; ws += cB * cH;
  float* hbA = ws; ws += cB * cH;  float* hbB = ws; ws += cB * cH;
  float* h0A = ws; ws += cB * cH;  float* h0B = ws; ws += cB * cH;
  float* h1A = ws; ws += cB * cH;  float* h1B = ws; ws += cB * cH;
  float* h2A = ws; ws += cB * cH;  float* h2B = ws; ws += cB * cH;
  float* zbuf  = ws; ws += cB * cZ;
  float* lgbuf = ws; ws += cB * cPF;
  ws = (float*)(((uintptr_t)ws + 255) & ~(uintptr_t)255);
  unsigned* barE = (unsigned*)ws;  ws += 2048;  // 4 domains x 512
  unsigned* barD = (unsigned*)ws;  ws += 1024;  // 1 domain (32 subs x 16)

  init_kernel<<<256, 256, 0, stream>>>(hfA, hbA, dout + (size_t)cB * cT * cPF, barE, barD);
  pad_wih_kernel<<<512, 256, 0, stream>>>(wih_f, wihfP);
  pad_wih_kernel<<<512, 256, 0, stream>>>(wih_b, wihbP);
  pad_x_kernel<<<2048, 256, 0, stream>>>(x, xp);
  pad_wsc_kernel<<<512, 256, 0, stream>>>(w_ih0, wsc);

  enc_persist<<<512, 512, 0, stream>>>(
      xp,
      wihfP, whh_f, bih_f, bhh_f,
      wihbP, whh_b, bih_b, bhh_b,
      hfA, hfB, hbA, hbB, barE);

  dec_persist<<<512, 512, 0, stream>>>(
      x, hfA, hbA,
      w_mu, b_mu, w_init, b_init,
      w_ih0, wsc, w_hh0, b_ih0, b_hh0,
      w_ih1, w_hh1, b_ih1, b_hh1,
      w_ih2, w_hh2, b_ih2, b_hh2,
      w_out, b_out,
      h0A, h0B, h1A, h1B, h2A, h2B,
      zbuf, lgbuf, dout, barD);
}

// Round 9
// 73821.606 us; speedup vs baseline: 1.1179x; 1.1179x over previous
//
#include <hip/hip_runtime.h>
#include <math.h>

namespace {

typedef unsigned long long u64;

constexpr int cH  = 1024;
constexpr int cZ  = 256;
constexpr int cB  = 64;
constexpr int cT  = 256;
constexpr int cR  = 389;
constexpr int cSC = 89;
constexpr int cPF = 300;
constexpr int WSTR = 400;               // padded encoder w_ih / x stride (floats) = 100 f4
constexpr float INV_S = 0.9999950000374997f;  // 1/sqrt(1+1e-5)

__device__ __forceinline__ void fma4(float4& a, const float4 x, const float4 w){
  a.x = fmaf(x.x, w.x, a.x);
  a.y = fmaf(x.y, w.y, a.y);
  a.z = fmaf(x.z, w.z, a.z);
  a.w = fmaf(x.w, w.w, a.w);
}
__device__ __forceinline__ float fold4(const float4 a){ return (a.x + a.y) + (a.z + a.w); }
__device__ __forceinline__ float4 z4(){ return make_float4(0.f, 0.f, 0.f, 0.f); }
__device__ __forceinline__ float sigm(float x){ return 1.f / (1.f + expf(-x)); }

// ---- coherent primitives ----
__device__ __forceinline__ void cfence(){ asm volatile("" ::: "memory"); }
// coherence-point 16B load (bypass L1+L2, wave-coalesced at the fabric)
__device__ __forceinline__ void ld_cg(float4& d, const float4* p){
  asm volatile("global_load_dwordx4 %0, %1, off sc0 sc1" : "=v"(d) : "v"(p) : "memory");
}
__device__ __forceinline__ void vm_drain(){
  asm volatile("s_waitcnt vmcnt(0)" ::: "memory");
  __builtin_amdgcn_sched_barrier(0);
}
__device__ __forceinline__ float ld_scal(const float* p){
  return __hip_atomic_load(p, __ATOMIC_RELAXED, __HIP_MEMORY_SCOPE_AGENT);
}
__device__ __forceinline__ void st_scal(float* p, float v){
  __hip_atomic_store(p, v, __ATOMIC_RELAXED, __HIP_MEMORY_SCOPE_AGENT);
}

// ---- two-level group barrier; RELEASE arrival orders prior agent stores ----
__device__ __forceinline__ void gbarN(unsigned* base, int sub, unsigned subCnt,
                                      int nsub, unsigned rootCnt){
  __syncthreads();
  if (threadIdx.x == 0){
    cfence();
    unsigned* root = base + nsub * 16;
    unsigned* gen  = base + nsub * 16 + 16;
    const unsigned g = __hip_atomic_load(gen, __ATOMIC_RELAXED, __HIP_MEMORY_SCOPE_AGENT);
    const unsigned a = __hip_atomic_fetch_add(base + sub * 16, 1u,
                         __ATOMIC_RELEASE, __HIP_MEMORY_SCOPE_AGENT);
    bool flip = false;
    if (a == subCnt - 1u){
      const unsigned r = __hip_atomic_fetch_add(root, 1u,
                           __ATOMIC_RELEASE, __HIP_MEMORY_SCOPE_AGENT);
      if (r == rootCnt - 1u){
        for (int t = 0; t < nsub; ++t)
          __hip_atomic_store(base + t * 16, 0u, __ATOMIC_RELAXED, __HIP_MEMORY_SCOPE_AGENT);
        __hip_atomic_store(root, 0u, __ATOMIC_RELAXED, __HIP_MEMORY_SCOPE_AGENT);
        __hip_atomic_store(gen, g + 1u, __ATOMIC_RELEASE, __HIP_MEMORY_SCOPE_AGENT);
        flip = true;
      }
    }
    if (!flip){
      while (__hip_atomic_load(gen, __ATOMIC_RELAXED, __HIP_MEMORY_SCOPE_AGENT) == g)
        __builtin_amdgcn_s_sleep(1);
    }
    cfence();
  }
  __syncthreads();
}

// ---------------------------------------------------------------- prep kernels
__global__ __launch_bounds__(256) void init_kernel(float* hf0, float* hb0, float* dout_tail,
                                                   unsigned* barE, unsigned* barD){
  const int idx = blockIdx.x * 256 + threadIdx.x;
  const int stride = gridDim.x * 256;
  for (int i = idx; i < cB * cH; i += stride){ hf0[i] = 0.f; hb0[i] = 0.f; }
  for (int i = idx; i < 2 * cB * cZ; i += stride) dout_tail[i] = 0.f;
  for (int i = idx; i < 2048; i += stride) barE[i] = 0u;
  for (int i = idx; i < 1024; i += stride) barD[i] = 0u;
}

__global__ __launch_bounds__(256) void pad_wih_kernel(const float* __restrict__ w,
                                                      float* __restrict__ wp){
  const int idx = blockIdx.x * 256 + threadIdx.x;
  const int stride = gridDim.x * 256;
  const int n = 3 * cH * WSTR;
  for (int i = idx; i < n; i += stride){
    const int r = i / WSTR, c = i - r * WSTR;
    wp[i] = (c < cR) ? w[(size_t)r * cR + c] : 0.f;
  }
}

__global__ __launch_bounds__(256) void pad_x_kernel(const float* __restrict__ x,
                                                    float* __restrict__ xp){
  const int idx = blockIdx.x * 256 + threadIdx.x;
  const int stride = gridDim.x * 256;
  const int n = cT * cB * WSTR;
  for (int i = idx; i < n; i += stride){
    const int r = i / WSTR, c = i - r * WSTR;
    xp[i] = (c < cR) ? x[(size_t)r * cR + c] : 0.f;
  }
}

__global__ __launch_bounds__(256) void pad_wsc_kernel(const float* __restrict__ w_ih0,
                                                      float* __restrict__ wsc){
  const int idx = blockIdx.x * 256 + threadIdx.x;
  const int stride = gridDim.x * 256;
  const int n = 3 * cH * 96;
  for (int i = idx; i < n; i += stride){
    const int r = i / 96, c = i - r * 96;
    wsc[i] = (c < cSC) ? w_ih0[(size_t)r * 645 + 300 + c] : 0.f;
  }
}

// ---------------------------------------------------------------- encoder (persistent)
// 512 blocks: xcd=bid&7, slot=bid>>3: dir=slot>>5, bhalf=(slot>>4)&1, k16=slot&15;
// kblk = xcd*16+k16 (8 k-rows), bhalf -> 32 batches.
__global__ __launch_bounds__(512, 4) void enc_persist(
    const float* __restrict__ xp,
    const float* __restrict__ wihPf, const float* __restrict__ whh_f,
    const float* __restrict__ bih_f, const float* __restrict__ bhh_f,
    const float* __restrict__ wihPb, const float* __restrict__ whh_b,
    const float* __restrict__ bih_b, const float* __restrict__ bhh_b,
    float* __restrict__ hfA, float* __restrict__ hfB,
    float* __restrict__ hbA, float* __restrict__ hbB,
    unsigned* __restrict__ barE)
{
  const int bid   = blockIdx.x;
  const int xcd   = bid & 7;
  const int slot  = bid >> 3;
  const int dir   = slot >> 5;
  const int bhalf = (slot >> 4) & 1;
  const int k16   = slot & 15;
  const int kblk  = xcd * 16 + k16;
  unsigned* bar   = barE + (dir * 2 + bhalf) * 512;

  const float* wih = dir ? wihPb : wihPf;
  const float* whh = dir ? whh_b : whh_f;
  const float* bih = dir ? bih_b : bih_f;
  const float* bhh = dir ? bhh_b : bhh_f;
  float* bufA = dir ? hbA : hfA;
  float* bufB = dir ? hbB : hfB;

  const int tid   = threadIdx.x;
  const int seg   = tid >> 6;            // 0..7
  const int lane  = tid & 63;
  const int tx    = lane & 7;
  const int ty    = lane >> 3;
  const int kbase = kblk * 8;
  const int bbase = bhalf * 32;
  const int k     = kbase + ty;

  __shared__ alignas(16) float sh[32 * 516];      // 66 KB: 32 rows x 129 f4
  float4* sh4 = (float4*)sh;
  float*  part = sh;                               // overlay, time-disjoint
  #define EPART(s,g,r,b) part[(((s)*4+(g))*8+(r))*33+(b)]

  const float4* w0i = (const float4*)wih + (size_t)k * 100;
  const float4* w1i = (const float4*)wih + (size_t)(cH + k) * 100;
  const float4* w2i = (const float4*)wih + (size_t)(2*cH + k) * 100;
  const float4* w0h = (const float4*)whh + (size_t)k * 256;
  const float4* w1h = (const float4*)whh + (size_t)(cH + k) * 256;
  const float4* w2h = (const float4*)whh + (size_t)(2*cH + k) * 256;

  auto stageE = [&](const float* hin, int p){
    const float4* s4 = (const float4*)hin;
    float4 r0,r1,r2,r3,r4,r5,r6,r7;
    ld_cg(r0, s4 + (size_t)(bbase + ((0*512+tid)>>7))*256 + p*128 + ((0*512+tid)&127));
    ld_cg(r1, s4 + (size_t)(bbase + ((1*512+tid)>>7))*256 + p*128 + ((1*512+tid)&127));
    ld_cg(r2, s4 + (size_t)(bbase + ((2*512+tid)>>7))*256 + p*128 + ((2*512+tid)&127));
    ld_cg(r3, s4 + (size_t)(bbase + ((3*512+tid)>>7))*256 + p*128 + ((3*512+tid)&127));
    ld_cg(r4, s4 + (size_t)(bbase + ((4*512+tid)>>7))*256 + p*128 + ((4*512+tid)&127));
    ld_cg(r5, s4 + (size_t)(bbase + ((5*512+tid)>>7))*256 + p*128 + ((5*512+tid)&127));
    ld_cg(r6, s4 + (size_t)(bbase + ((6*512+tid)>>7))*256 + p*128 + ((6*512+tid)&127));
    ld_cg(r7, s4 + (size_t)(bbase + ((7*512+tid)>>7))*256 + p*128 + ((7*512+tid)&127));
    vm_drain();
    sh4[((0*512+tid)>>7)*129 + ((0*512+tid)&127)] = r0;
    sh4[((1*512+tid)>>7)*129 + ((1*512+tid)&127)] = r1;
    sh4[((2*512+tid)>>7)*129 + ((2*512+tid)&127)] = r2;
    sh4[((3*512+tid)>>7)*129 + ((3*512+tid)&127)] = r3;
    sh4[((4*512+tid)>>7)*129 + ((4*512+tid)&127)] = r4;
    sh4[((5*512+tid)>>7)*129 + ((5*512+tid)&127)] = r5;
    sh4[((6*512+tid)>>7)*129 + ((6*512+tid)&127)] = r6;
    sh4[((7*512+tid)>>7)*129 + ((7*512+tid)&127)] = r7;
  };

  for (int t = 0; t < cT; ++t){
    const float* hin = (t & 1) ? bufB : bufA;
    float*      hout = (t & 1) ? bufA : bufB;
    const int tt = dir ? (cT - 1 - t) : t;

    float4 R[4], Z[4], NI[4], NH[4];
    #pragma unroll
    for (int jj = 0; jj < 4; ++jj){ R[jj]=z4(); Z[jj]=z4(); NI[jj]=z4(); NH[jj]=z4(); }

    // ---- phase 1: x @ w_ih^T (padded f4)
    {
      const float4* xr[4];
      #pragma unroll
      for (int jj = 0; jj < 4; ++jj)
        xr[jj] = (const float4*)xp + (size_t)(tt * cB + bbase + tx + 8*jj) * 100;
      const int c0 = seg * 13;
      const int c1 = (c0 + 13 < 100) ? c0 + 13 : 100;
      for (int c = c0; c < c1; ++c){
        const float4 w0v = w0i[c], w1v = w1i[c], w2v = w2i[c];
        #pragma unroll
        for (int jj = 0; jj < 4; ++jj){
          const float4 a = xr[jj][c];
          fma4(R[jj], a, w0v); fma4(Z[jj], a, w1v); fma4(NI[jj], a, w2v);
        }
      }
    }

    // ---- phase 2: h @ w_hh^T, two staged halves
    #pragma unroll 1
    for (int p = 0; p < 2; ++p){
      stageE(hin, p);
      __syncthreads();
      {
        const float4* wp0 = w0h + p * 128;
        const float4* wp1 = w1h + p * 128;
        const float4* wp2 = w2h + p * 128;
        #pragma unroll 4
        for (int c = 0; c < 16; ++c){
          const int cc = seg * 16 + c;
          const float4 w0v = wp0[cc], w1v = wp1[cc], w2v = wp2[cc];
          #pragma unroll
          for (int jj = 0; jj < 4; ++jj){
            const float4 a = sh4[(tx + 8*jj)*129 + cc];
            fma4(R[jj], a, w0v); fma4(Z[jj], a, w1v); fma4(NH[jj], a, w2v);
          }
        }
      }
      __syncthreads();
    }

    #pragma unroll
    for (int jj = 0; jj < 4; ++jj){
      const int b = tx + 8*jj;
      EPART(seg,0,ty,b) = fold4(R[jj]);
      EPART(seg,1,ty,b) = fold4(Z[jj]);
      EPART(seg,2,ty,b) = fold4(NI[jj]);
      EPART(seg,3,ty,b) = fold4(NH[jj]);
    }
    __syncthreads();
    if (tid < 256){
      const int row = tid >> 5, bb = tid & 31;
      float rs=0.f, zs=0.f, nis=0.f, nhs=0.f;
      #pragma unroll
      for (int s = 0; s < 8; ++s){
        rs += EPART(s,0,row,bb); zs += EPART(s,1,row,bb);
        nis += EPART(s,2,row,bb); nhs += EPART(s,3,row,bb);
      }
      const int kk = kbase + row, gb = bbase + bb;
      const float r  = sigm(rs + bih[kk] + bhh[kk]);
      const float zg = sigm(zs + bih[cH + kk] + bhh[cH + kk]);
      const float nn = tanhf(nis + bih[2*cH + kk] + r * (nhs + bhh[2*cH + kk]));
      const float hp = ld_scal(&hin[(size_t)gb * cH + kk]);
      st_scal(&hout[(size_t)gb * cH + kk], (1.f - zg) * nn + zg * hp);
    }
    gbarN(bar, k16, 8u, 16, 16u);
  }
  #undef EPART
}

// ---------------------------------------------------------------- decoder (persistent)
// 512 blocks: xcd=bid&7, slot=bid>>3; kq = xcd*8 + (slot>>3) (0..63, 16 k-rows),
// bq = slot&7 (8 batches).  One 512-block barrier domain (32 subs x 16).
// tid 512: seg=tid>>6 (8 col-segs of 32 f4); lane: ty=lane>>2 (16 rows), tx=lane&3;
// batches b = tx + 4*jj (jj 0..1).
__global__ __launch_bounds__(512, 4) void dec_persist(
    const float* __restrict__ x,
    const float* __restrict__ hfA, const float* __restrict__ hbA,
    const float* __restrict__ w_mu, const float* __restrict__ b_mu,
    const float* __restrict__ w_init, const float* __restrict__ b_init,
    const float* __restrict__ w_ih0,
    const float* __restrict__ wsc,   const float* __restrict__ w_hh0,
    const float* __restrict__ b_ih0, const float* __restrict__ b_hh0,
    const float* __restrict__ w_ih1, const float* __restrict__ w_hh1,
    const float* __restrict__ b_ih1, const float* __restrict__ b_hh1,
    const float* __restrict__ w_ih2, const float* __restrict__ w_hh2,
    const float* __restrict__ b_ih2, const float* __restrict__ b_hh2,
    const float* __restrict__ w_out, const float* __restrict__ b_out,
    float* __restrict__ h0A, float* __restrict__ h0B,
    float* __restrict__ h1A, float* __restrict__ h1B,
    float* __restrict__ h2A, float* __restrict__ h2B,
    float* __restrict__ zbuf, float* __restrict__ lgbuf,
    float* __restrict__ dout,
    unsigned* __restrict__ barD)
{
  const int bid  = blockIdx.x;
  const int xcd  = bid & 7;
  const int slot = bid >> 3;
  const int kq   = xcd * 8 + (slot >> 3);
  const int bq   = slot & 7;
  const int kbase = kq * 16;
  const int bbase = bq * 8;
  const int tid = threadIdx.x;

  const int seg  = tid >> 6;
  const int lane = tid & 63;
  const int tx   = lane & 3;
  const int ty   = lane >> 2;            // 0..15
  const int k    = kbase + ty;

  __shared__ alignas(16) float arena[8 * 1028];    // 32.9 KB (stage 8 rows x 257 f4; LG/z overlay)
  __shared__ float part[8][4][16][9];              // 18.4 KB
  __shared__ alignas(16) float scs[8 * 100];       // 3.2 KB
  __shared__ float ams[8];
  __shared__ float gz[3][16][8];

  float4* stg4 = (float4*)arena;

  #define GBD gbarN(barD, bid >> 4, 16u, 32, 32u)

  auto stageH = [&](const float* src){
    const float4* s4 = (const float4*)src;
    float4 r0,r1,r2,r3;
    ld_cg(r0, s4 + (size_t)(bbase + ((0*512+tid)>>8))*256 + ((0*512+tid)&255));
    ld_cg(r1, s4 + (size_t)(bbase + ((1*512+tid)>>8))*256 + ((1*512+tid)&255));
    ld_cg(r2, s4 + (size_t)(bbase + ((2*512+tid)>>8))*256 + ((2*512+tid)&255));
    ld_cg(r3, s4 + (size_t)(bbase + ((3*512+tid)>>8))*256 + ((3*512+tid)&255));
    vm_drain();
    stg4[((0*512+tid)>>8)*257 + ((0*512+tid)&255)] = r0;
    stg4[((1*512+tid)>>8)*257 + ((1*512+tid)&255)] = r1;
    stg4[((2*512+tid)>>8)*257 + ((2*512+tid)&255)] = r2;
    stg4[((3*512+tid)>>8)*257 + ((3*512+tid)&255)] = r3;
  };

  auto accH = [&](const float4* w0, const float4* w1, const float4* w2,
                  float4& A0, float4& A1, float4& B0, float4& B1,
                  float4& C0, float4& C1){
    #pragma unroll 4
    for (int c = 0; c < 32; ++c){
      const int cc = seg * 32 + c;
      const float4 w0v = w0[cc], w1v = w1[cc], w2v = w2[cc];
      const float4 aA = stg4[tx * 257 + cc];
      const float4 aB = stg4[(tx + 4) * 257 + cc];
      fma4(A0, aA, w0v); fma4(B0, aA, w1v); fma4(C0, aA, w2v);
      fma4(A1, aB, w0v); fma4(B1, aB, w1v); fma4(C1, aB, w2v);
    }
  };

  auto reduce_store = [&](const float* bi, const float* bhv,
                          const float* hprev, float* hout){
    __syncthreads();
    if (tid < 128){
      const int row = tid >> 3, b = tid & 7;
      float rs=0.f, zs=0.f, nis=0.f, nhs=0.f;
      #pragma unroll
      for (int s = 0; s < 8; ++s){
        rs += part[s][0][row][b]; zs += part[s][1][row][b];
        nis += part[s][2][row][b]; nhs += part[s][3][row][b];
      }
      const int kk = kbase + row, gb = bbase + b;
      const float r  = sigm(rs + bi[kk] + bhv[kk]);
      const float zg = sigm(zs + bi[cH + kk] + bhv[cH + kk]);
      const float nn = tanhf(nis + bi[2*cH + kk] + r * (nhs + bhv[2*cH + kk]));
      const float hp = ld_scal(&hprev[(size_t)gb * cH + kk]);
      st_scal(&hout[(size_t)gb * cH + kk], (1.f - zg) * nn + zg * hp);
    }
  };

  // fold: 8 teams (waves) x 8 batches; arena overlay rows 304 floats
  auto fold8 = [&](int jm1, bool writeAms){
    const int team = tid >> 6, l64 = tid & 63;
    const int gb = bbase + team;
    {
      const float4* lb4 = (const float4*)lgbuf;
      float4 v0, v1;
      const int i2 = (64 + l64 < 75) ? (64 + l64) : 74;
      ld_cg(v0, lb4 + (size_t)gb * 75 + l64);
      ld_cg(v1, lb4 + (size_t)gb * 75 + i2);
      vm_drain();
      ((float4*)(arena + team * 304))[l64] = v0;
      if (64 + l64 < 75) ((float4*)(arena + team * 304))[64 + l64] = v1;
    }
    __syncthreads();
    const float* lgr = arena + team * 304;
    float m[3], lse[3];
    #pragma unroll
    for (int g3 = 0; g3 < 3; ++g3){
      float mm = -INFINITY;
      for (int p = g3*100 + l64; p < g3*100 + 100; p += 64) mm = fmaxf(mm, lgr[p]);
      #pragma unroll
      for (int off = 32; off > 0; off >>= 1) mm = fmaxf(mm, __shfl_xor(mm, off));
      float ss = 0.f;
      for (int p = g3*100 + l64; p < g3*100 + 100; p += 64) ss += expf(lgr[p] - mm);
      #pragma unroll
      for (int off = 32; off > 0; off >>= 1) ss += __shfl_xor(ss, off);
      m[g3] = mm; lse[g3] = logf(ss);
    }
    float best = -INFINITY; int bidx = 0x7fffffff;
    for (int p = l64; p < cPF; p += 64){
      const int g3 = (p >= 200) ? 2 : ((p >= 100) ? 1 : 0);
      const float o = lgr[p] - m[g3] - lse[g3];
      if (kq == 0) dout[((size_t)gb * cT + jm1) * cPF + p] = o;
      if (o > best || (o == best && p < bidx)){ best = o; bidx = p; }
    }
    if (writeAms){
      #pragma unroll
      for (int off = 32; off > 0; off >>= 1){
        const float ob = __shfl_xor(best, off);
        const int   oi = __shfl_xor(bidx, off);
        if (ob > best || (ob == best && oi < bidx)){ best = ob; bidx = oi; }
      }
      if (l64 == 0) ams[team] = (float)bidx;
    }
  };

  // ================= prologue =================
  if (bid < cB){
    const int b = bid;
    float4* hl4 = (float4*)arena;
    hl4[tid] = (tid < 256) ? ((const float4*)hfA)[(size_t)b * 256 + tid]
                           : ((const float4*)hbA)[(size_t)b * 256 + (tid - 256)];
    __syncthreads();
    if (tid < 256){
      const float4* wr = (const float4*)w_mu + (size_t)tid * 512;
      float4 s = z4();
      #pragma unroll 4
      for (int c = 0; c < 512; ++c) fma4(s, hl4[c], wr[c]);
      st_scal(&zbuf[(size_t)b * cZ + tid], b_mu[tid] + fold4(s) * INV_S);
    }
  }
  GBD;
  {
    // stage z for this block's 8 batches (row stride 260 floats = 65 f4)
    {
      float4 v;
      const int row = tid >> 6, col = tid & 63;
      ld_cg(v, (const float4*)zbuf + (size_t)(bbase + row) * 64 + col);
      vm_drain();
      ((float4*)arena)[row * 65 + col] = v;
    }
    __syncthreads();
    if (tid < 384){                         // gz: 3 gates x 16 rows x 8 batches
      const int g = tid >> 7, kr = (tid >> 3) & 15, b = tid & 7;
      const float* zr = arena + b * 260;
      const float* wrow = w_ih0 + (size_t)(g * cH + kbase + kr) * 645 + 389;
      float s = 0.f;
      #pragma unroll 4
      for (int d = 0; d < cZ; ++d) s = fmaf(zr[d], wrow[d], s);
      gz[g][kr][b] = s;
    }
    if (tid < 128){                         // hinit: 16 rows x 8 batches
      const int kr = tid >> 3, b = tid & 7;
      const float4* zr4 = (const float4*)(arena + b * 260);
      const float4* wr4 = (const float4*)w_init + (size_t)(kbase + kr) * 64;
      float4 s = z4();
      #pragma unroll 4
      for (int d = 0; d < 64; ++d) fma4(s, zr4[d], wr4[d]);
      st_scal(&h0A[(size_t)(bbase + b) * cH + kbase + kr],
              tanhf(b_init[kbase + kr] + fold4(s)));
    }
    __syncthreads();
  }
  GBD;

  // ================= main loop =================
  for (int j = 0; j < cT; ++j){
    const int par = j & 1;
    const float* h0p = par ? h0B : h0A;  float* h0n = par ? h0A : h0B;
    const float* h1p = par ? h1B : h1A;  float* h1n = par ? h1A : h1B;
    const float* h2p = par ? h2B : h2A;  float* h2n = par ? h2A : h2B;

    // ---- phase A: fold(prev) + layer 0
    {
      if (j == 0){
        if (tid < 8) ams[tid] = 299.f;
        const int team = tid >> 6, l64 = tid & 63;
        for (int c = l64; c < 96; c += 64) scs[team * 100 + c] = (c == 88) ? 1.f : 0.f;
      } else {
        fold8(j - 1, true);
        __syncthreads();
        const int team = tid >> 6, l64 = tid & 63;
        const int gb = bbase + team;
        for (int c = l64; c < 96; c += 64)
          scs[team * 100 + c] = (c < cSC) ? x[((size_t)(j - 1) * cB + gb) * cR + c] : 0.f;
      }
      __syncthreads();

      float4 R[2], Z[2], NI[2], NH[2];
      float sR[2], sZ[2], sNI[2];
      #pragma unroll
      for (int jj = 0; jj < 2; ++jj){
        R[jj]=z4(); Z[jj]=z4(); NI[jj]=z4(); NH[jj]=z4();
        sR[jj]=0.f; sZ[jj]=0.f; sNI[jj]=0.f;
      }
      {  // score GEMM: cols seg*3..+3 of 24 f4
        const float4* ws0 = (const float4*)wsc + (size_t)k * 24;
        const float4* ws1 = (const float4*)wsc + (size_t)(cH + k) * 24;
        const float4* ws2 = (const float4*)wsc + (size_t)(2*cH + k) * 24;
        const float4* sc4 = (const float4*)scs;
        #pragma unroll
        for (int c = 0; c < 3; ++c){
          const int cc = seg * 3 + c;
          const float4 w0v = ws0[cc], w1v = ws1[cc], w2v = ws2[cc];
          #pragma unroll
          for (int jj = 0; jj < 2; ++jj){
            const float4 a = sc4[(tx + 4*jj) * 25 + cc];
            fma4(R[jj], a, w0v); fma4(Z[jj], a, w1v); fma4(NI[jj], a, w2v);
          }
        }
      }
      if (seg == 0){  // one-hot gather + precomputed z-part
        #pragma unroll
        for (int jj = 0; jj < 2; ++jj){
          const int b = tx + 4*jj;
          const int am = (int)ams[b];
          sR[jj]  = w_ih0[(size_t)k * 645 + am]          + gz[0][ty][b];
          sZ[jj]  = w_ih0[(size_t)(cH + k) * 645 + am]   + gz[1][ty][b];
          sNI[jj] = w_ih0[(size_t)(2*cH + k) * 645 + am] + gz[2][ty][b];
        }
      }
      const float4* wh0 = (const float4*)w_hh0 + (size_t)k * 256;
      const float4* wh1 = (const float4*)w_hh0 + (size_t)(cH + k) * 256;
      const float4* wh2 = (const float4*)w_hh0 + (size_t)(2*cH + k) * 256;
      __syncthreads();
      stageH(h0p);  __syncthreads();
      accH(wh0, wh1, wh2, R[0], R[1], Z[0], Z[1], NH[0], NH[1]);
      #pragma unroll
      for (int jj = 0; jj < 2; ++jj){
        const int b = tx + 4*jj;
        part[seg][0][ty][b] = fold4(R[jj]) + sR[jj];
        part[seg][1][ty][b] = fold4(Z[jj]) + sZ[jj];
        part[seg][2][ty][b] = fold4(NI[jj]) + sNI[jj];
        part[seg][3][ty][b] = fold4(NH[jj]);
      }
      reduce_store(b_ih0, b_hh0, h0p, h0n);
    }
    GBD;

    // ---- phases B, C: layers 1, 2
    #pragma unroll 1
    for (int L = 0; L < 2; ++L){
      const float* inG = (L == 0) ? h0n : h1n;
      const float* pvG = (L == 0) ? (j == 0 ? h0n : h1p) : (j == 0 ? h1n : h2p);
      const float* wih = (L == 0) ? w_ih1 : w_ih2;
      const float* whh = (L == 0) ? w_hh1 : w_hh2;
      const float* bi  = (L == 0) ? b_ih1 : b_ih2;
      const float* bhv = (L == 0) ? b_hh1 : b_hh2;
      float* outG      = (L == 0) ? h1n : h2n;

      float4 R[2], Z[2], NI[2], NH[2];
      #pragma unroll
      for (int jj = 0; jj < 2; ++jj){ R[jj]=z4(); Z[jj]=z4(); NI[jj]=z4(); NH[jj]=z4(); }
      const float4* wi0 = (const float4*)wih + (size_t)k * 256;
      const float4* wi1 = (const float4*)wih + (size_t)(cH + k) * 256;
      const float4* wi2 = (const float4*)wih + (size_t)(2*cH + k) * 256;
      const float4* wh0 = (const float4*)whh + (size_t)k * 256;
      const float4* wh1 = (const float4*)whh + (size_t)(cH + k) * 256;
      const float4* wh2 = (const float4*)whh + (size_t)(2*cH + k) * 256;

      stageH(inG);  __syncthreads();
      accH(wi0, wi1, wi2, R[0], R[1], Z[0], Z[1], NI[0], NI[1]);
      __syncthreads();
      stageH(pvG);  __syncthreads();
      accH(wh0, wh1, wh2, R[0], R[1], Z[0], Z[1], NH[0], NH[1]);
      #pragma unroll
      for (int jj = 0; jj < 2; ++jj){
        const int b = tx + 4*jj;
        part[seg][0][ty][b] = fold4(R[jj]);
        part[seg][1][ty][b] = fold4(Z[jj]);
        part[seg][2][ty][b] = fold4(NI[jj]);
        part[seg][3][ty][b] = fold4(NH[jj]);
      }
      reduce_store(bi, bhv, pvG, outG);
      GBD;
    }

    // ---- phase D: distributed logits -> lgbuf (4-5 p-rows per kq)
    {
      const int p0 = (kq * 300) >> 6;
      const int p1 = ((kq + 1) * 300) >> 6;
      stageH(h2n);  __syncthreads();
      const int b8 = tid >> 6;            // 0..7
      const int cs = tid & 63;            // 0..63
      for (int pr = p0; pr < p1; ++pr){
        const float4* wr = (const float4*)w_out + (size_t)pr * 256;
        const float4* av = stg4 + b8 * 257;
        float4 s = z4();
        #pragma unroll
        for (int u = 0; u < 4; ++u){
          const int cc = cs + u * 64;
          fma4(s, av[cc], wr[cc]);
        }
        float v = fold4(s);
        #pragma unroll
        for (int off = 32; off > 0; off >>= 1) v += __shfl_xor(v, off);
        if (cs == 0)
          st_scal(&lgbuf[(size_t)(bbase + b8) * cPF + pr], v + b_out[pr]);
      }
      __syncthreads();
    }
    GBD;
  }

  // tail: fold for step 255 (dout only)
  if (kq == 0) fold8(cT - 1, false);
  #undef GBD
}

} // namespace

// ---------------------------------------------------------------- host
extern "C" void kernel_launch(void* const* d_in, const int* in_sizes, int n_in,
                              void* d_out, int out_size, void* d_ws, size_t ws_size,
                              hipStream_t stream)
{
  const float* x     = (const float*)d_in[0];
  const float* wih_f = (const float*)d_in[2];
  const float* whh_f = (const float*)d_in[3];
  const float* bih_f = (const float*)d_in[4];
  const float* bhh_f = (const float*)d_in[5];
  const float* wih_b = (const float*)d_in[6];
  const float* whh_b = (const float*)d_in[7];
  const float* bih_b = (const float*)d_in[8];
  const float* bhh_b = (const float*)d_in[9];
  const float* w_mu  = (const float*)d_in[10];
  const float* b_mu  = (const float*)d_in[11];
  const float* w_init= (const float*)d_in[14];
  const float* b_init= (const float*)d_in[15];
  const float* w_ih0 = (const float*)d_in[16];
  const float* w_hh0 = (const float*)d_in[17];
  const float* b_ih0 = (const float*)d_in[18];
  const float* b_hh0 = (const float*)d_in[19];
  const float* w_ih1 = (const float*)d_in[20];
  const float* w_hh1 = (const float*)d_in[21];
  const float* b_ih1 = (const float*)d_in[22];
  const float* b_hh1 = (const float*)d_in[23];
  const float* w_ih2 = (const float*)d_in[24];
  const float* w_hh2 = (const float*)d_in[25];
  const float* b_ih2 = (const float*)d_in[26];
  const float* b_hh2 = (const float*)d_in[27];
  const float* w_out = (const float*)d_in[28];
  const float* b_out = (const float*)d_in[29];
  float* dout = (float*)d_out;

  float* ws = (float*)d_ws;
  float* wihfP = ws; ws += (size_t)3 * cH * WSTR;     // 4.9 MB
  float* wihbP = ws; ws += (size_t)3 * cH * WSTR;     // 4.9 MB
  float* xp    = ws; ws += (size_t)cT * cB * WSTR;    // 26.2 MB
  float* wsc   = ws; ws += (size_t)3 * cH * 96;       // 1.2 MB
  float* hfA = ws; ws += cB * cH;  float* hfB = ws; ws += cB * cH;
  float* hbA = ws; ws += cB * cH;  float* hbB = ws; ws += cB * cH;
  float* h0A = ws; ws += cB * cH;  float* h0B = ws; ws += cB * cH;
  float* h1A = ws; ws += cB * cH;  float* h1B = ws; ws += cB * cH;
  float* h2A = ws; ws += cB * cH;  float* h2B = ws; ws += cB * cH;
  float* zbuf  = ws; ws += cB * cZ;
  float* lgbuf = ws; ws += cB * cPF;
  ws = (float*)(((uintptr_t)ws + 255) & ~(uintptr_t)255);
  unsigned* barE = (unsigned*)ws;  ws += 2048;  // 4 domains x 512
  unsigned* barD = (unsigned*)ws;  ws += 1024;  // 1 domain (32 subs x 16)

  init_kernel<<<256, 256, 0, stream>>>(hfA, hbA, dout + (size_t)cB * cT * cPF, barE, barD);
  pad_wih_kernel<<<512, 256, 0, stream>>>(wih_f, wihfP);
  pad_wih_kernel<<<512, 256, 0, stream>>>(wih_b, wihbP);
  pad_x_kernel<<<2048, 256, 0, stream>>>(x, xp);
  pad_wsc_kernel<<<512, 256, 0, stream>>>(w_ih0, wsc);

  enc_persist<<<512, 512, 0, stream>>>(
      xp,
      wihfP, whh_f, bih_f, bhh_f,
      wihbP, whh_b, bih_b, bhh_b,
      hfA, hfB, hbA, hbB, barE);

  dec_persist<<<512, 512, 0, stream>>>(
      x, hfA, hbA,
      w_mu, b_mu, w_init, b_init,
      w_ih0, wsc, w_hh0, b_ih0, b_hh0,
      w_ih1, w_hh1, b_ih1, b_hh1,
      w_ih2, w_hh2, b_ih2, b_hh2,
      w_out, b_out,
      h0A, h0B, h1A, h1B, h2A, h2B,
      zbuf, lgbuf, dout, barD);
}